// Round 2
// baseline (274.196 us; speedup 1.0000x reference)
//
#include <hip/hip_runtime.h>
#include <hip/hip_bf16.h>

#define NN 50000
#define NE 1600000
#define DD 128
#define NB 196        // 256-node bins: ceil(50000/256)
#define NCH 256       // edge chunks
#define PER 6250      // NE / NCH
#define NT 8          // src tiles (1.6MB each -> ~2 fit an XCD L2)
#define TS 6250       // nodes per src tile

typedef short bfrag __attribute__((ext_vector_type(8)));   // 8 bf16 = 4 VGPR
typedef float ffrag __attribute__((ext_vector_type(4)));   // 4 f32 acc
typedef float f32x2 __attribute__((ext_vector_type(2)));   // packed f32 pair

__device__ __forceinline__ float bf2f(unsigned short u) {
    union { unsigned int i; float f; } c; c.i = ((unsigned int)u) << 16; return c.f;
}
__device__ __forceinline__ unsigned short f2bf(float f) {
    __hip_bfloat16 h = __float2bfloat16(f);
    union { __hip_bfloat16 h; unsigned short u; } c; c.h = h; return c.u;
}
__device__ __forceinline__ int insane_bf16(unsigned short u) {
    unsigned e = (u >> 7) & 0xFF;
    return (e == 0xFF) || (e >= 0x8E);
}

// flags[0]=indices int64; flags[1]=feat f32 (=> out f32); flags[2]=W f32
__global__ void k_detect(const int* __restrict__ srcw, const int* __restrict__ dstw,
                         const unsigned short* __restrict__ feat16,
                         const unsigned short* __restrict__ w16,
                         int* __restrict__ flags) {
    __shared__ int s_idx, s_feat, s_w;
    int tid = threadIdx.x;
    if (tid == 0) { s_idx = 0; s_feat = 0; s_w = 0; }
    __syncthreads();
    if (tid < 64) {
        int v = srcw[2 * tid + 1] | dstw[2 * tid + 1];
        if (v) atomicOr(&s_idx, 1);
    }
    if (insane_bf16(feat16[2 * tid]) || insane_bf16(feat16[2 * tid + 512]))
        atomicOr(&s_feat, 1);
    if (insane_bf16(w16[2 * tid]) || insane_bf16(w16[2 * tid + 512]))
        atomicOr(&s_w, 1);
    __syncthreads();
    if (tid == 0) { flags[0] = (s_idx == 0) ? 1 : 0; flags[1] = s_feat; flags[2] = s_w; }
}

__device__ __forceinline__ int load_idx(const void* p, int e, int is64) {
    long long v = is64 ? ((const long long*)p)[e] : (long long)((const int*)p)[e];
    int i = (int)v;
    return (i < 0) ? 0 : (i >= NN ? NN - 1 : i);
}

// chunk-block counts its edges per bin
__global__ __launch_bounds__(256) void k_count(const void* __restrict__ dst,
        int* __restrict__ cnt, const int* __restrict__ flags) {
    __shared__ int lc[NB];
    int c = blockIdx.x, tid = threadIdx.x;
    if (tid < NB) lc[tid] = 0;
    __syncthreads();
    int lo = c * PER, hi = lo + PER; if (hi > NE) hi = NE;
    int is64 = flags[0];
    for (int e = lo + tid; e < hi; e += 256)
        atomicAdd(&lc[load_idx(dst, e, is64) >> 8], 1);
    __syncthreads();
    if (tid < NB) cnt[tid * NCH + c] = lc[tid];
}

// per-bin exclusive scan over chunks
__global__ __launch_bounds__(256) void k_scan2(const int* __restrict__ cnt,
        int* __restrict__ loff, int* __restrict__ binsum) {
    __shared__ int buf[256];
    int b = blockIdx.x, tid = threadIdx.x;
    int v = cnt[b * NCH + tid];
    buf[tid] = v;
    __syncthreads();
    for (int off = 1; off < 256; off <<= 1) {
        int t = (tid >= off) ? buf[tid - off] : 0;
        __syncthreads();
        buf[tid] += t;
        __syncthreads();
    }
    loff[b * NCH + tid] = buf[tid] - v;
    if (tid == 255) binsum[b] = buf[255];
}

// scan bin totals -> binoff[0..NB]; rowptr[NN]=NE
__global__ __launch_bounds__(256) void k_scanbin(const int* __restrict__ binsum,
        int* __restrict__ binoff, int* __restrict__ rowptr) {
    __shared__ int buf[256];
    int tid = threadIdx.x;
    int v = (tid < NB) ? binsum[tid] : 0;
    buf[tid] = v;
    __syncthreads();
    for (int off = 1; off < 256; off <<= 1) {
        int t = (tid >= off) ? buf[tid - off] : 0;
        __syncthreads();
        buf[tid] += t;
        __syncthreads();
    }
    if (tid < NB) binoff[tid] = buf[tid] - v;
    if (tid == NB - 1) binoff[NB] = buf[tid];
    if (tid == 0) rowptr[NN] = NE;
}

// chunk-block places edges into bin-major staged[] via precomputed offsets
__global__ __launch_bounds__(256) void k_stage(const void* __restrict__ src,
        const void* __restrict__ dst, const int* __restrict__ binoff,
        const int* __restrict__ loff, unsigned* __restrict__ staged,
        const int* __restrict__ flags) {
    __shared__ int cur[NB];
    int c = blockIdx.x, tid = threadIdx.x;
    if (tid < NB) cur[tid] = binoff[tid] + loff[tid * NCH + c];
    __syncthreads();
    int lo = c * PER, hi = lo + PER; if (hi > NE) hi = NE;
    int is64 = flags[0];
    for (int e = lo + tid; e < hi; e += 256) {
        int d = load_idx(dst, e, is64);
        int s = load_idx(src, e, is64);
        int pos = atomicAdd(&cur[d >> 8], 1);
        staged[pos] = ((unsigned)(d & 255) << 16) | (unsigned)s;
    }
}

// bin-block: (node,tile) LDS count -> scan -> rowptr/norm -> tile-grouped scatter
// srclist entries are pre-scaled to element offsets (s * DD) for the gather.
__global__ __launch_bounds__(512) void k_fill(const unsigned* __restrict__ staged,
        const int* __restrict__ binoff, int* __restrict__ rowptr,
        float* __restrict__ norm, int* __restrict__ srclist) {
    __shared__ int cnt4[256 * NT];
    __shared__ int ntot[256];
    int b = blockIdx.x, tid = threadIdx.x;
    int lo = binoff[b], hi = binoff[b + 1];
    for (int i = tid; i < 256 * NT; i += 512) cnt4[i] = 0;
    __syncthreads();
    for (int k = lo + tid; k < hi; k += 512) {
        unsigned u = staged[k];
        atomicAdd(&cnt4[(u >> 16) * NT + (int)(u & 0xffff) / TS], 1);
    }
    __syncthreads();
    if (tid < 256) {
        int s = 0;
        #pragma unroll
        for (int t = 0; t < NT; ++t) s += cnt4[tid * NT + t];
        ntot[tid] = s;
    }
    __syncthreads();
    for (int off = 1; off < 256; off <<= 1) {
        int t = 0;
        if (tid < 256 && tid >= off) t = ntot[tid - off];
        __syncthreads();
        if (tid < 256) ntot[tid] += t;
        __syncthreads();
    }
    if (tid < 256) {
        int deg = 0;
        #pragma unroll
        for (int t = 0; t < NT; ++t) deg += cnt4[tid * NT + t];
        int start = lo + ntot[tid] - deg;
        int n = b * 256 + tid;
        if (n < NN) {
            rowptr[n] = start;
            norm[n] = rsqrtf(fmaxf((float)deg, 1.0f));
        }
        int c = start;
        #pragma unroll
        for (int t = 0; t < NT; ++t) {
            int v = cnt4[tid * NT + t];
            cnt4[tid * NT + t] = c;
            c += v;
        }
    }
    __syncthreads();
    for (int k = lo + tid; k < hi; k += 512) {
        unsigned u = staged[k];
        int s = (int)(u & 0xffff);
        int pos = atomicAdd(&cnt4[(u >> 16) * NT + s / TS], 1);
        srclist[pos] = s << 7;   // element offset: s * DD
    }
}

// X1[n,d] = feat[n,d] * norm[n]  (bf16)
__global__ void k_prescale(const void* __restrict__ feat,
                           const float* __restrict__ norm,
                           unsigned short* __restrict__ X,
                           const int* __restrict__ flags) {
    int i = blockIdx.x * 256 + threadIdx.x;
    if (i >= NN * DD / 4) return;
    float nm = norm[i >> 5];
    float4 v;
    if (flags[1]) {
        v = ((const float4*)feat)[i];
    } else {
        ushort4 f = ((const ushort4*)feat)[i];
        v.x = bf2f(f.x); v.y = bf2f(f.y); v.z = bf2f(f.z); v.w = bf2f(f.w);
    }
    ushort4 o;
    o.x = f2bf(v.x * nm); o.y = f2bf(v.y * nm);
    o.z = f2bf(v.z * nm); o.w = f2bf(v.w * nm);
    ((ushort4*)X)[i] = o;
}

// packed bf16-pair -> f32x2 (1 shift + 1 and), accumulate via v_pk_add_f32
__device__ __forceinline__ f32x2 bfpair(unsigned u) {
    union { unsigned i; float f; } lo, hi;
    lo.i = u << 16;
    hi.i = u & 0xffff0000u;
    f32x2 r; r[0] = lo.f; r[1] = hi.f; return r;
}
__device__ __forceinline__ void accp(f32x2* a, uint4 v) {
    a[0] += bfpair(v.x);
    a[1] += bfpair(v.y);
    a[2] += bfpair(v.z);
    a[3] += bfpair(v.w);
}

// gather-reduce: one wave per dst node; 4 edge-slots x 16 lanes x 16B rows.
// Main loop covers 32 edges (the average degree) per wave-iter: 8 independent
// row loads per lane issued back-to-back, so the whole average segment has 8
// loads in flight during its single VALU burst. srclist entries are element
// offsets (s*DD), removing the per-edge multiply.
// mode 0: out = bf16(acc * norm^2) -> X2;  mode 1: out = bf16(acc * norm) -> Yb
__global__ __launch_bounds__(256, 6) void k_gather(const unsigned short* __restrict__ Xin,
        const int* __restrict__ rowptr, const int* __restrict__ srclist,
        const float* __restrict__ norm, unsigned short* __restrict__ outp,
        int mode) {
    int wid = (blockIdx.x * 256 + threadIdx.x) >> 6;
    int lane = threadIdx.x & 63;
    if (wid >= NN) return;
    int beg = rowptr[wid], end = rowptr[wid + 1];
    int g = lane >> 4;
    int c8 = (lane & 15) << 3;
    const unsigned short* xb = Xin + c8;
    f32x2 a[4];
    #pragma unroll
    for (int k = 0; k < 4; ++k) a[k] = (f32x2){0.f, 0.f};

    int j = beg + g;
    for (; j + 28 < end; j += 32) {
        int s0 = srclist[j];
        int s1 = srclist[j + 4];
        int s2 = srclist[j + 8];
        int s3 = srclist[j + 12];
        int s4 = srclist[j + 16];
        int s5 = srclist[j + 20];
        int s6 = srclist[j + 24];
        int s7 = srclist[j + 28];
        uint4 r0 = *(const uint4*)(xb + s0);
        uint4 r1 = *(const uint4*)(xb + s1);
        uint4 r2 = *(const uint4*)(xb + s2);
        uint4 r3 = *(const uint4*)(xb + s3);
        uint4 r4 = *(const uint4*)(xb + s4);
        uint4 r5 = *(const uint4*)(xb + s5);
        uint4 r6 = *(const uint4*)(xb + s6);
        uint4 r7 = *(const uint4*)(xb + s7);
        accp(a, r0); accp(a, r1); accp(a, r2); accp(a, r3);
        accp(a, r4); accp(a, r5); accp(a, r6); accp(a, r7);
    }
    for (; j + 12 < end; j += 16) {
        int s0 = srclist[j];
        int s1 = srclist[j + 4];
        int s2 = srclist[j + 8];
        int s3 = srclist[j + 12];
        uint4 r0 = *(const uint4*)(xb + s0);
        uint4 r1 = *(const uint4*)(xb + s1);
        uint4 r2 = *(const uint4*)(xb + s2);
        uint4 r3 = *(const uint4*)(xb + s3);
        accp(a, r0); accp(a, r1); accp(a, r2); accp(a, r3);
    }
    for (; j < end; j += 4) {
        int s = srclist[j];
        uint4 v = *(const uint4*)(xb + s);
        accp(a, v);
    }
    #pragma unroll
    for (int k = 0; k < 4; ++k) {
        a[k][0] += __shfl_xor(a[k][0], 16);
        a[k][1] += __shfl_xor(a[k][1], 16);
        a[k][0] += __shfl_xor(a[k][0], 32);
        a[k][1] += __shfl_xor(a[k][1], 32);
    }

    if (g == 0) {
        float nm = norm[wid];
        float sc = (mode == 0) ? nm * nm : nm;
        uint4 o;
        o.x = ((unsigned)f2bf(a[0][1] * sc) << 16) | (unsigned)f2bf(a[0][0] * sc);
        o.y = ((unsigned)f2bf(a[1][1] * sc) << 16) | (unsigned)f2bf(a[1][0] * sc);
        o.z = ((unsigned)f2bf(a[2][1] * sc) << 16) | (unsigned)f2bf(a[2][0] * sc);
        o.w = ((unsigned)f2bf(a[3][1] * sc) << 16) | (unsigned)f2bf(a[3][0] * sc);
        *(uint4*)(outp + wid * DD + c8) = o;
    }
}

// MFMA GEMM: out[n,o] = Yb[n,:] @ W[o,:] + b[o].  Yb bf16 (norm applied).
__global__ __launch_bounds__(256) void k_gemm2(const unsigned short* __restrict__ Yb,
        const void* __restrict__ Wp, const void* __restrict__ bp,
        void* __restrict__ outp, const int* __restrict__ flags) {
    __shared__ unsigned short Wl[DD * 136];
    int tid = threadIdx.x;
    int wf32 = flags[2], of32 = flags[1];

    for (int i = tid; i < 8192; i += 256) {
        int r = i >> 6, cc = i & 63;
        unsigned pk;
        if (wf32) {
            float2 w = ((const float2*)Wp)[i];
            pk = ((unsigned)f2bf(w.y) << 16) | (unsigned)f2bf(w.x);
        } else {
            pk = ((const unsigned*)Wp)[i];
        }
        *(unsigned*)&Wl[r * 136 + cc * 2] = pk;
    }
    __syncthreads();

    int wave = tid >> 6, lane = tid & 63;
    int nb = blockIdx.x * 64 + wave * 16;
    int m = lane & 15, quad = lane >> 4;
    int arow = nb + m; if (arow >= NN) arow = NN - 1;
    const unsigned short* arp = Yb + arow * DD + quad * 8;

    ffrag acc[8];
    #pragma unroll
    for (int t = 0; t < 8; ++t) acc[t] = (ffrag){0.f, 0.f, 0.f, 0.f};

    #pragma unroll
    for (int c = 0; c < 4; ++c) {
        bfrag af = *(const bfrag*)(arp + c * 32);
        #pragma unroll
        for (int t = 0; t < 8; ++t) {
            bfrag bf = *(const bfrag*)&Wl[(t * 16 + m) * 136 + c * 32 + quad * 8];
            acc[t] = __builtin_amdgcn_mfma_f32_16x16x32_bf16(af, bf, acc[t], 0, 0, 0);
        }
    }

    #pragma unroll
    for (int t = 0; t < 8; ++t) {
        int o = t * 16 + m;
        float bias = wf32 ? ((const float*)bp)[o] : bf2f(((const unsigned short*)bp)[o]);
        #pragma unroll
        for (int r = 0; r < 4; ++r) {
            int n = nb + quad * 4 + r;
            if (n < NN) {
                float v = acc[t][r] + bias;
                if (of32) ((float*)outp)[n * DD + o] = v;
                else      ((unsigned short*)outp)[n * DD + o] = f2bf(v);
            }
        }
    }
}

extern "C" void kernel_launch(void* const* d_in, const int* in_sizes, int n_in,
                              void* d_out, int out_size, void* d_ws, size_t ws_size,
                              hipStream_t stream) {
    const void* feat = d_in[0];
    const void* src  = d_in[1];
    const void* dst  = d_in[2];
    const void* W    = d_in[3];
    const void* b    = d_in[4];

    // ws (bytes): flags@0 | rowptr@64 | norm@200128 | cnt@400128 | loff@600832 |
    //   binsum@801536 | binoff@802560 | srclist@803584 | X1@7203584 | X2@20003584
    //   staged aliases X2's first 6.4MB (dead before gather-0 writes X2). end 32.8MB
    char* wsb = (char*)d_ws;
    int*   flags   = (int*)wsb;
    int*   rowptr  = (int*)(wsb + 64);
    float* norm    = (float*)(wsb + 200128);
    int*   cnt     = (int*)(wsb + 400128);
    int*   loff    = (int*)(wsb + 600832);
    int*   binsum  = (int*)(wsb + 801536);
    int*   binoff  = (int*)(wsb + 802560);
    int*   srclist = (int*)(wsb + 803584);
    unsigned short* X1 = (unsigned short*)(wsb + 7203584);   // hop-1 input, then Yb
    unsigned short* X2 = (unsigned short*)(wsb + 20003584);
    unsigned* staged   = (unsigned*)(wsb + 20003584);

    k_detect<<<1, 256, 0, stream>>>((const int*)src, (const int*)dst,
                                    (const unsigned short*)feat,
                                    (const unsigned short*)W, flags);
    k_count<<<NCH, 256, 0, stream>>>(dst, cnt, flags);
    k_scan2<<<NB, 256, 0, stream>>>(cnt, loff, binsum);
    k_scanbin<<<1, 256, 0, stream>>>(binsum, binoff, rowptr);
    k_stage<<<NCH, 256, 0, stream>>>(src, dst, binoff, loff, staged, flags);
    k_fill<<<NB, 512, 0, stream>>>(staged, binoff, rowptr, norm, srclist);
    k_prescale<<<(NN * DD / 4 + 255) / 256, 256, 0, stream>>>(feat, norm, X1, flags);
    k_gather<<<(NN + 3) / 4, 256, 0, stream>>>(X1, rowptr, srclist, norm, X2, 0);
    k_gather<<<(NN + 3) / 4, 256, 0, stream>>>(X2, rowptr, srclist, norm, X1, 1);
    k_gemm2<<<(NN + 63) / 64, 256, 0, stream>>>(X1, W, b, d_out, flags);
}

// Round 4
// 259.517 us; speedup vs baseline: 1.0566x; 1.0566x over previous
//
#include <hip/hip_runtime.h>
#include <hip/hip_bf16.h>

#define NN 50000
#define NE 1600000
#define DD 128
#define NB 196        // 256-node bins: ceil(50000/256)
#define NCH 256       // edge chunks
#define PER 6250      // NE / NCH
#define NT 4          // src tiles
#define TS 12500      // nodes per src tile
#define ZOFF (NN * DD)   // element offset of the all-zero guard row

typedef short bfrag __attribute__((ext_vector_type(8)));   // 8 bf16 = 4 VGPR
typedef float ffrag __attribute__((ext_vector_type(4)));   // 4 f32 acc
typedef float f32x2 __attribute__((ext_vector_type(2)));   // packed f32 pair

__device__ __forceinline__ float bf2f(unsigned short u) {
    union { unsigned int i; float f; } c; c.i = ((unsigned int)u) << 16; return c.f;
}
__device__ __forceinline__ unsigned short f2bf(float f) {
    __hip_bfloat16 h = __float2bfloat16(f);
    union { __hip_bfloat16 h; unsigned short u; } c; c.h = h; return c.u;
}
__device__ __forceinline__ int insane_bf16(unsigned short u) {
    unsigned e = (u >> 7) & 0xFF;
    return (e == 0xFF) || (e >= 0x8E);
}

// flags[0]=indices int64; flags[1]=feat f32 (=> out f32); flags[2]=W f32
__global__ void k_detect(const int* __restrict__ srcw, const int* __restrict__ dstw,
                         const unsigned short* __restrict__ feat16,
                         const unsigned short* __restrict__ w16,
                         int* __restrict__ flags) {
    __shared__ int s_idx, s_feat, s_w;
    int tid = threadIdx.x;
    if (tid == 0) { s_idx = 0; s_feat = 0; s_w = 0; }
    __syncthreads();
    if (tid < 64) {
        int v = srcw[2 * tid + 1] | dstw[2 * tid + 1];
        if (v) atomicOr(&s_idx, 1);
    }
    if (insane_bf16(feat16[2 * tid]) || insane_bf16(feat16[2 * tid + 512]))
        atomicOr(&s_feat, 1);
    if (insane_bf16(w16[2 * tid]) || insane_bf16(w16[2 * tid + 512]))
        atomicOr(&s_w, 1);
    __syncthreads();
    if (tid == 0) { flags[0] = (s_idx == 0) ? 1 : 0; flags[1] = s_feat; flags[2] = s_w; }
}

__device__ __forceinline__ int load_idx(const void* p, int e, int is64) {
    long long v = is64 ? ((const long long*)p)[e] : (long long)((const int*)p)[e];
    int i = (int)v;
    return (i < 0) ? 0 : (i >= NN ? NN - 1 : i);
}

// chunk-block counts its edges per bin
__global__ __launch_bounds__(256) void k_count(const void* __restrict__ dst,
        int* __restrict__ cnt, const int* __restrict__ flags) {
    __shared__ int lc[NB];
    int c = blockIdx.x, tid = threadIdx.x;
    if (tid < NB) lc[tid] = 0;
    __syncthreads();
    int lo = c * PER, hi = lo + PER; if (hi > NE) hi = NE;
    int is64 = flags[0];
    for (int e = lo + tid; e < hi; e += 256)
        atomicAdd(&lc[load_idx(dst, e, is64) >> 8], 1);
    __syncthreads();
    if (tid < NB) cnt[tid * NCH + c] = lc[tid];
}

// per-bin exclusive scan over chunks
__global__ __launch_bounds__(256) void k_scan2(const int* __restrict__ cnt,
        int* __restrict__ loff, int* __restrict__ binsum) {
    __shared__ int buf[256];
    int b = blockIdx.x, tid = threadIdx.x;
    int v = cnt[b * NCH + tid];
    buf[tid] = v;
    __syncthreads();
    for (int off = 1; off < 256; off <<= 1) {
        int t = (tid >= off) ? buf[tid - off] : 0;
        __syncthreads();
        buf[tid] += t;
        __syncthreads();
    }
    loff[b * NCH + tid] = buf[tid] - v;
    if (tid == 255) binsum[b] = buf[255];
}

// scan bin totals -> binoff[0..NB]; rowptr[NN]=NE
__global__ __launch_bounds__(256) void k_scanbin(const int* __restrict__ binsum,
        int* __restrict__ binoff, int* __restrict__ rowptr) {
    __shared__ int buf[256];
    int tid = threadIdx.x;
    int v = (tid < NB) ? binsum[tid] : 0;
    buf[tid] = v;
    __syncthreads();
    for (int off = 1; off < 256; off <<= 1) {
        int t = (tid >= off) ? buf[tid - off] : 0;
        __syncthreads();
        buf[tid] += t;
        __syncthreads();
    }
    if (tid < NB) binoff[tid] = buf[tid] - v;
    if (tid == NB - 1) binoff[NB] = buf[tid];
    if (tid == 0) rowptr[NN] = NE;
}

// chunk-block places edges into bin-major staged[] via precomputed offsets
__global__ __launch_bounds__(256) void k_stage(const void* __restrict__ src,
        const void* __restrict__ dst, const int* __restrict__ binoff,
        const int* __restrict__ loff, unsigned* __restrict__ staged,
        const int* __restrict__ flags) {
    __shared__ int cur[NB];
    int c = blockIdx.x, tid = threadIdx.x;
    if (tid < NB) cur[tid] = binoff[tid] + loff[tid * NCH + c];
    __syncthreads();
    int lo = c * PER, hi = lo + PER; if (hi > NE) hi = NE;
    int is64 = flags[0];
    for (int e = lo + tid; e < hi; e += 256) {
        int d = load_idx(dst, e, is64);
        int s = load_idx(src, e, is64);
        int pos = atomicAdd(&cur[d >> 8], 1);
        staged[pos] = ((unsigned)(d & 255) << 16) | (unsigned)s;
    }
}

// bin-block: (node,tile) LDS count -> scan -> rowptr/norm -> tile-grouped scatter
// srclist entries are pre-scaled to element offsets (s * DD) for the gather.
__global__ __launch_bounds__(512) void k_fill(const unsigned* __restrict__ staged,
        const int* __restrict__ binoff, int* __restrict__ rowptr,
        float* __restrict__ norm, int* __restrict__ srclist) {
    __shared__ int cnt4[256 * NT];
    __shared__ int ntot[256];
    int b = blockIdx.x, tid = threadIdx.x;
    int lo = binoff[b], hi = binoff[b + 1];
    for (int i = tid; i < 256 * NT; i += 512) cnt4[i] = 0;
    __syncthreads();
    for (int k = lo + tid; k < hi; k += 512) {
        unsigned u = staged[k];
        atomicAdd(&cnt4[(u >> 16) * NT + (int)(u & 0xffff) / TS], 1);
    }
    __syncthreads();
    if (tid < 256) {
        int s = 0;
        #pragma unroll
        for (int t = 0; t < NT; ++t) s += cnt4[tid * NT + t];
        ntot[tid] = s;
    }
    __syncthreads();
    for (int off = 1; off < 256; off <<= 1) {
        int t = 0;
        if (tid < 256 && tid >= off) t = ntot[tid - off];
        __syncthreads();
        if (tid < 256) ntot[tid] += t;
        __syncthreads();
    }
    if (tid < 256) {
        int deg = 0;
        #pragma unroll
        for (int t = 0; t < NT; ++t) deg += cnt4[tid * NT + t];
        int start = lo + ntot[tid] - deg;
        int n = b * 256 + tid;
        if (n < NN) {
            rowptr[n] = start;
            norm[n] = rsqrtf(fmaxf((float)deg, 1.0f));
        }
        int c = start;
        #pragma unroll
        for (int t = 0; t < NT; ++t) {
            int v = cnt4[tid * NT + t];
            cnt4[tid * NT + t] = c;
            c += v;
        }
    }
    __syncthreads();
    for (int k = lo + tid; k < hi; k += 512) {
        unsigned u = staged[k];
        int s = (int)(u & 0xffff);
        int pos = atomicAdd(&cnt4[(u >> 16) * NT + s / TS], 1);
        srclist[pos] = s << 7;   // element offset: s * DD
    }
}

// X1[n,d] = feat[n,d] * norm[n] (bf16); also zeroes the guard rows of X1 and X2.
__global__ void k_prescale(const void* __restrict__ feat,
                           const float* __restrict__ norm,
                           unsigned short* __restrict__ X,
                           unsigned short* __restrict__ X2,
                           const int* __restrict__ flags) {
    int i = blockIdx.x * 256 + threadIdx.x;
    const int total = NN * DD / 4;
    if (i >= total) {
        int r = i - total;
        ushort4 z; z.x = 0; z.y = 0; z.z = 0; z.w = 0;
        if (r < 32)      ((ushort4*)X)[total + r] = z;         // X1 zero row
        else if (r < 64) ((ushort4*)X2)[total + (r - 32)] = z; // X2 zero row
        return;
    }
    float nm = norm[i >> 5];
    float4 v;
    if (flags[1]) {
        v = ((const float4*)feat)[i];
    } else {
        ushort4 f = ((const ushort4*)feat)[i];
        v.x = bf2f(f.x); v.y = bf2f(f.y); v.z = bf2f(f.z); v.w = bf2f(f.w);
    }
    ushort4 o;
    o.x = f2bf(v.x * nm); o.y = f2bf(v.y * nm);
    o.z = f2bf(v.z * nm); o.w = f2bf(v.w * nm);
    ((ushort4*)X)[i] = o;
}

// packed bf16-pair -> f32x2 (1 shift + 1 and), accumulate via v_pk_add_f32
__device__ __forceinline__ f32x2 bfpair(unsigned u) {
    union { unsigned i; float f; } lo, hi;
    lo.i = u << 16;
    hi.i = u & 0xffff0000u;
    f32x2 r; r[0] = lo.f; r[1] = hi.f; return r;
}
__device__ __forceinline__ void accp(f32x2* a, uint4 v) {
    a[0] += bfpair(v.x);
    a[1] += bfpair(v.y);
    a[2] += bfpair(v.z);
    a[3] += bfpair(v.w);
}

// gather-reduce: one wave per dst node; 4 edge-slots x 16 lanes x 16B rows.
// Per 64-edge window: ONE coalesced srclist load into the wave's lanes, then
// row addresses come from __shfl. The shfl executes UNCONDITIONALLY at wave
// scope (all 64 lanes active; divergent-exec bpermute reads undefined data
// from inactive lanes -- the round-3 bug); masked slots select the zero
// guard row (ZOFF) afterwards via cndmask. 8 independent 16B row loads in
// flight per lane per batch.
// mode 0: out = bf16(acc * norm^2) -> X2;  mode 1: out = bf16(acc * norm) -> Yb
__global__ __launch_bounds__(256) void k_gather(const unsigned short* __restrict__ Xin,
        const int* __restrict__ rowptr, const int* __restrict__ srclist,
        const float* __restrict__ norm, unsigned short* __restrict__ outp,
        int mode) {
    int wid = (blockIdx.x * 256 + threadIdx.x) >> 6;
    int lane = threadIdx.x & 63;
    if (wid >= NN) return;
    int beg = rowptr[wid], end = rowptr[wid + 1];
    int g = lane >> 4;
    int c8 = (lane & 15) << 3;
    const unsigned short* xb = Xin + c8;
    f32x2 a[4];
    #pragma unroll
    for (int k = 0; k < 4; ++k) a[k] = (f32x2){0.f, 0.f};

    int j = beg;
    while (j < end) {
        int n = end - j;
        if (n > 64) n = 64;
        int li = (lane < n) ? lane : (n - 1);
        int sv = srclist[j + li];
        {
            uint4 r[8];
            #pragma unroll
            for (int i = 0; i < 8; ++i) {
                int k = g + 4 * i;                       // k in [0,32)
                int s = __shfl(sv, k);                   // convergent, whole wave
                s = (k < n) ? s : ZOFF;                  // per-lane select
                r[i] = *(const uint4*)(xb + s);
            }
            #pragma unroll
            for (int i = 0; i < 8; ++i) accp(a, r[i]);
        }
        if (n > 32) {                                    // wave-uniform branch
            uint4 r[8];
            #pragma unroll
            for (int i = 0; i < 8; ++i) {
                int k = 32 + g + 4 * i;                  // k in [32,64)
                int s = __shfl(sv, k);
                s = (k < n) ? s : ZOFF;
                r[i] = *(const uint4*)(xb + s);
            }
            #pragma unroll
            for (int i = 0; i < 8; ++i) accp(a, r[i]);
        }
        j += n;
    }
    #pragma unroll
    for (int k = 0; k < 4; ++k) {
        a[k][0] += __shfl_xor(a[k][0], 16);
        a[k][1] += __shfl_xor(a[k][1], 16);
        a[k][0] += __shfl_xor(a[k][0], 32);
        a[k][1] += __shfl_xor(a[k][1], 32);
    }

    if (g == 0) {
        float nm = norm[wid];
        float sc = (mode == 0) ? nm * nm : nm;
        uint4 o;
        o.x = ((unsigned)f2bf(a[0][1] * sc) << 16) | (unsigned)f2bf(a[0][0] * sc);
        o.y = ((unsigned)f2bf(a[1][1] * sc) << 16) | (unsigned)f2bf(a[1][0] * sc);
        o.z = ((unsigned)f2bf(a[2][1] * sc) << 16) | (unsigned)f2bf(a[2][0] * sc);
        o.w = ((unsigned)f2bf(a[3][1] * sc) << 16) | (unsigned)f2bf(a[3][0] * sc);
        *(uint4*)(outp + wid * DD + c8) = o;
    }
}

// MFMA GEMM: out[n,o] = Yb[n,:] @ W[o,:] + b[o].  Yb bf16 (norm applied).
__global__ __launch_bounds__(256) void k_gemm2(const unsigned short* __restrict__ Yb,
        const void* __restrict__ Wp, const void* __restrict__ bp,
        void* __restrict__ outp, const int* __restrict__ flags) {
    __shared__ unsigned short Wl[DD * 136];
    int tid = threadIdx.x;
    int wf32 = flags[2], of32 = flags[1];

    for (int i = tid; i < 8192; i += 256) {
        int r = i >> 6, cc = i & 63;
        unsigned pk;
        if (wf32) {
            float2 w = ((const float2*)Wp)[i];
            pk = ((unsigned)f2bf(w.y) << 16) | (unsigned)f2bf(w.x);
        } else {
            pk = ((const unsigned*)Wp)[i];
        }
        *(unsigned*)&Wl[r * 136 + cc * 2] = pk;
    }
    __syncthreads();

    int wave = tid >> 6, lane = tid & 63;
    int nb = blockIdx.x * 64 + wave * 16;
    int m = lane & 15, quad = lane >> 4;
    int arow = nb + m; if (arow >= NN) arow = NN - 1;
    const unsigned short* arp = Yb + arow * DD + quad * 8;

    ffrag acc[8];
    #pragma unroll
    for (int t = 0; t < 8; ++t) acc[t] = (ffrag){0.f, 0.f, 0.f, 0.f};

    #pragma unroll
    for (int c = 0; c < 4; ++c) {
        bfrag af = *(const bfrag*)(arp + c * 32);
        #pragma unroll
        for (int t = 0; t < 8; ++t) {
            bfrag bf = *(const bfrag*)&Wl[(t * 16 + m) * 136 + c * 32 + quad * 8];
            acc[t] = __builtin_amdgcn_mfma_f32_16x16x32_bf16(af, bf, acc[t], 0, 0, 0);
        }
    }

    #pragma unroll
    for (int t = 0; t < 8; ++t) {
        int o = t * 16 + m;
        float bias = wf32 ? ((const float*)bp)[o] : bf2f(((const unsigned short*)bp)[o]);
        #pragma unroll
        for (int r = 0; r < 4; ++r) {
            int n = nb + quad * 4 + r;
            if (n < NN) {
                float v = acc[t][r] + bias;
                if (of32) ((float*)outp)[n * DD + o] = v;
                else      ((unsigned short*)outp)[n * DD + o] = f2bf(v);
            }
        }
    }
}

extern "C" void kernel_launch(void* const* d_in, const int* in_sizes, int n_in,
                              void* d_out, int out_size, void* d_ws, size_t ws_size,
                              hipStream_t stream) {
    const void* feat = d_in[0];
    const void* src  = d_in[1];
    const void* dst  = d_in[2];
    const void* W    = d_in[3];
    const void* b    = d_in[4];

    // ws (bytes): flags@0 | rowptr@64 | norm@200128 | cnt@400128 | loff@600832 |
    //   binsum@801536 | binoff@802560 | srclist@803584 | X1@7203584 (+zero row) |
    //   X2@20003840 (+zero row). staged aliases X2's first 6.4MB (dead before
    //   gather-0 writes X2). end 32804096 (~32.8MB)
    char* wsb = (char*)d_ws;
    int*   flags   = (int*)wsb;
    int*   rowptr  = (int*)(wsb + 64);
    float* norm    = (float*)(wsb + 200128);
    int*   cnt     = (int*)(wsb + 400128);
    int*   loff    = (int*)(wsb + 600832);
    int*   binsum  = (int*)(wsb + 801536);
    int*   binoff  = (int*)(wsb + 802560);
    int*   srclist = (int*)(wsb + 803584);
    unsigned short* X1 = (unsigned short*)(wsb + 7203584);   // hop-1 input, then Yb
    unsigned short* X2 = (unsigned short*)(wsb + 20003840);
    unsigned* staged   = (unsigned*)(wsb + 20003840);

    k_detect<<<1, 256, 0, stream>>>((const int*)src, (const int*)dst,
                                    (const unsigned short*)feat,
                                    (const unsigned short*)W, flags);
    k_count<<<NCH, 256, 0, stream>>>(dst, cnt, flags);
    k_scan2<<<NB, 256, 0, stream>>>(cnt, loff, binsum);
    k_scanbin<<<1, 256, 0, stream>>>(binsum, binoff, rowptr);
    k_stage<<<NCH, 256, 0, stream>>>(src, dst, binoff, loff, staged, flags);
    k_fill<<<NB, 512, 0, stream>>>(staged, binoff, rowptr, norm, srclist);
    k_prescale<<<NN * DD / 4 / 256 + 1, 256, 0, stream>>>(feat, norm, X1, X2, flags);
    k_gather<<<(NN + 3) / 4, 256, 0, stream>>>(X1, rowptr, srclist, norm, X2, 0);
    k_gather<<<(NN + 3) / 4, 256, 0, stream>>>(X2, rowptr, srclist, norm, X1, 1);
    k_gemm2<<<(NN + 63) / 64, 256, 0, stream>>>(X1, W, b, d_out, flags);
}

// Round 5
// 235.633 us; speedup vs baseline: 1.1637x; 1.1014x over previous
//
#include <hip/hip_runtime.h>
#include <hip/hip_bf16.h>

#define NN 50000
#define NE 1600000
#define DD 128
#define NB 196        // 256-node bins: ceil(50000/256)
#define NCH 256       // edge chunks
#define PER 6250      // NE / NCH
#define NT 4          // src tiles
#define TS 12500      // nodes per src tile
#define GWAVE 6252    // gather waves: ceil(NN/8)
#define GBLK 1563     // GWAVE/4 blocks of 256

typedef short bfrag __attribute__((ext_vector_type(8)));   // 8 bf16 = 4 VGPR
typedef float ffrag __attribute__((ext_vector_type(4)));   // 4 f32 acc
typedef float f32x2 __attribute__((ext_vector_type(2)));   // packed f32 pair

__device__ __forceinline__ float bf2f(unsigned short u) {
    union { unsigned int i; float f; } c; c.i = ((unsigned int)u) << 16; return c.f;
}
__device__ __forceinline__ unsigned short f2bf(float f) {
    __hip_bfloat16 h = __float2bfloat16(f);
    union { __hip_bfloat16 h; unsigned short u; } c; c.h = h; return c.u;
}
__device__ __forceinline__ int insane_bf16(unsigned short u) {
    unsigned e = (u >> 7) & 0xFF;
    return (e == 0xFF) || (e >= 0x8E);
}

// flags[0]=indices int64; flags[1]=feat f32 (=> out f32); flags[2]=W f32
__global__ void k_detect(const int* __restrict__ srcw, const int* __restrict__ dstw,
                         const unsigned short* __restrict__ feat16,
                         const unsigned short* __restrict__ w16,
                         int* __restrict__ flags) {
    __shared__ int s_idx, s_feat, s_w;
    int tid = threadIdx.x;
    if (tid == 0) { s_idx = 0; s_feat = 0; s_w = 0; }
    __syncthreads();
    if (tid < 64) {
        int v = srcw[2 * tid + 1] | dstw[2 * tid + 1];
        if (v) atomicOr(&s_idx, 1);
    }
    if (insane_bf16(feat16[2 * tid]) || insane_bf16(feat16[2 * tid + 512]))
        atomicOr(&s_feat, 1);
    if (insane_bf16(w16[2 * tid]) || insane_bf16(w16[2 * tid + 512]))
        atomicOr(&s_w, 1);
    __syncthreads();
    if (tid == 0) { flags[0] = (s_idx == 0) ? 1 : 0; flags[1] = s_feat; flags[2] = s_w; }
}

__device__ __forceinline__ int load_idx(const void* p, int e, int is64) {
    long long v = is64 ? ((const long long*)p)[e] : (long long)((const int*)p)[e];
    int i = (int)v;
    return (i < 0) ? 0 : (i >= NN ? NN - 1 : i);
}

// chunk-block counts its edges per bin
__global__ __launch_bounds__(256) void k_count(const void* __restrict__ dst,
        int* __restrict__ cnt, const int* __restrict__ flags) {
    __shared__ int lc[NB];
    int c = blockIdx.x, tid = threadIdx.x;
    if (tid < NB) lc[tid] = 0;
    __syncthreads();
    int lo = c * PER, hi = lo + PER; if (hi > NE) hi = NE;
    int is64 = flags[0];
    for (int e = lo + tid; e < hi; e += 256)
        atomicAdd(&lc[load_idx(dst, e, is64) >> 8], 1);
    __syncthreads();
    if (tid < NB) cnt[tid * NCH + c] = lc[tid];
}

// per-bin exclusive scan over chunks
__global__ __launch_bounds__(256) void k_scan2(const int* __restrict__ cnt,
        int* __restrict__ loff, int* __restrict__ binsum) {
    __shared__ int buf[256];
    int b = blockIdx.x, tid = threadIdx.x;
    int v = cnt[b * NCH + tid];
    buf[tid] = v;
    __syncthreads();
    for (int off = 1; off < 256; off <<= 1) {
        int t = (tid >= off) ? buf[tid - off] : 0;
        __syncthreads();
        buf[tid] += t;
        __syncthreads();
    }
    loff[b * NCH + tid] = buf[tid] - v;
    if (tid == 255) binsum[b] = buf[255];
}

// scan bin totals -> binoff[0..NB]; rowptr[NN]=NE
__global__ __launch_bounds__(256) void k_scanbin(const int* __restrict__ binsum,
        int* __restrict__ binoff, int* __restrict__ rowptr) {
    __shared__ int buf[256];
    int tid = threadIdx.x;
    int v = (tid < NB) ? binsum[tid] : 0;
    buf[tid] = v;
    __syncthreads();
    for (int off = 1; off < 256; off <<= 1) {
        int t = (tid >= off) ? buf[tid - off] : 0;
        __syncthreads();
        buf[tid] += t;
        __syncthreads();
    }
    if (tid < NB) binoff[tid] = buf[tid] - v;
    if (tid == NB - 1) binoff[NB] = buf[tid];
    if (tid == 0) rowptr[NN] = NE;
}

// chunk-block places edges into bin-major staged[] via precomputed offsets
__global__ __launch_bounds__(256) void k_stage(const void* __restrict__ src,
        const void* __restrict__ dst, const int* __restrict__ binoff,
        const int* __restrict__ loff, unsigned* __restrict__ staged,
        const int* __restrict__ flags) {
    __shared__ int cur[NB];
    int c = blockIdx.x, tid = threadIdx.x;
    if (tid < NB) cur[tid] = binoff[tid] + loff[tid * NCH + c];
    __syncthreads();
    int lo = c * PER, hi = lo + PER; if (hi > NE) hi = NE;
    int is64 = flags[0];
    for (int e = lo + tid; e < hi; e += 256) {
        int d = load_idx(dst, e, is64);
        int s = load_idx(src, e, is64);
        int pos = atomicAdd(&cur[d >> 8], 1);
        staged[pos] = ((unsigned)(d & 255) << 16) | (unsigned)s;
    }
}

// bin-block: (node,tile) LDS count -> scan -> rowptr/tptr/norm -> tile-grouped
// scatter. srclist entries pre-scaled to element offsets (s * DD).
// tptr[n] = int4 of the 4 per-tile segment starts (seg t ends at next start,
// tile 3 ends at rowptr[n+1]).
__global__ __launch_bounds__(512) void k_fill(const unsigned* __restrict__ staged,
        const int* __restrict__ binoff, int* __restrict__ rowptr,
        int4* __restrict__ tptr,
        float* __restrict__ norm, int* __restrict__ srclist) {
    __shared__ int cnt4[256 * NT];
    __shared__ int ntot[256];
    int b = blockIdx.x, tid = threadIdx.x;
    int lo = binoff[b], hi = binoff[b + 1];
    for (int i = tid; i < 256 * NT; i += 512) cnt4[i] = 0;
    __syncthreads();
    for (int k = lo + tid; k < hi; k += 512) {
        unsigned u = staged[k];
        atomicAdd(&cnt4[(u >> 16) * NT + (int)(u & 0xffff) / TS], 1);
    }
    __syncthreads();
    if (tid < 256)
        ntot[tid] = cnt4[tid * NT] + cnt4[tid * NT + 1]
                  + cnt4[tid * NT + 2] + cnt4[tid * NT + 3];
    __syncthreads();
    for (int off = 1; off < 256; off <<= 1) {
        int t = 0;
        if (tid < 256 && tid >= off) t = ntot[tid - off];
        __syncthreads();
        if (tid < 256) ntot[tid] += t;
        __syncthreads();
    }
    if (tid < 256) {
        int v0 = cnt4[tid * NT], v1 = cnt4[tid * NT + 1];
        int v2 = cnt4[tid * NT + 2], v3 = cnt4[tid * NT + 3];
        int deg = v0 + v1 + v2 + v3;
        int start = lo + ntot[tid] - deg;
        int n = b * 256 + tid;
        int4 tp;
        tp.x = start;
        tp.y = start + v0;
        tp.z = start + v0 + v1;
        tp.w = start + v0 + v1 + v2;
        if (n < NN) {
            rowptr[n] = start;
            norm[n] = rsqrtf(fmaxf((float)deg, 1.0f));
            tptr[n] = tp;
        }
        cnt4[tid * NT + 0] = tp.x;
        cnt4[tid * NT + 1] = tp.y;
        cnt4[tid * NT + 2] = tp.z;
        cnt4[tid * NT + 3] = tp.w;
    }
    __syncthreads();
    for (int k = lo + tid; k < hi; k += 512) {
        unsigned u = staged[k];
        int s = (int)(u & 0xffff);
        int pos = atomicAdd(&cnt4[(u >> 16) * NT + s / TS], 1);
        srclist[pos] = s << 7;   // element offset: s * DD
    }
}

// X1[n,d] = feat[n,d] * norm[n]  (bf16)
__global__ void k_prescale(const void* __restrict__ feat,
                           const float* __restrict__ norm,
                           unsigned short* __restrict__ X,
                           const int* __restrict__ flags) {
    int i = blockIdx.x * 256 + threadIdx.x;
    if (i >= NN * DD / 4) return;
    float nm = norm[i >> 5];
    float4 v;
    if (flags[1]) {
        v = ((const float4*)feat)[i];
    } else {
        ushort4 f = ((const ushort4*)feat)[i];
        v.x = bf2f(f.x); v.y = bf2f(f.y); v.z = bf2f(f.z); v.w = bf2f(f.w);
    }
    ushort4 o;
    o.x = f2bf(v.x * nm); o.y = f2bf(v.y * nm);
    o.z = f2bf(v.z * nm); o.w = f2bf(v.w * nm);
    ((ushort4*)X)[i] = o;
}

// packed bf16-pair -> f32x2 (1 shift + 1 and), accumulate via v_pk_add_f32
__device__ __forceinline__ f32x2 bfpair(unsigned u) {
    union { unsigned i; float f; } lo, hi;
    lo.i = u << 16;
    hi.i = u & 0xffff0000u;
    f32x2 r; r[0] = lo.f; r[1] = hi.f; return r;
}
__device__ __forceinline__ void accp(f32x2* a, uint4 v) {
    a[0] += bfpair(v.x);
    a[1] += bfpair(v.y);
    a[2] += bfpair(v.z);
    a[3] += bfpair(v.w);
}

// Tile-phase-aligned persistent gather.
// Grid = GBLK blocks (all co-resident): 6252 waves, each owning 8 dst nodes
// (two quads of 4). Lane groups of 16 own one node each (full 256B row via
// 16 x uint4); acc = 8 f32/lane per quad -- no cross-lane reduce needed.
// Loop is TILE-MAJOR (t outer), so all resident waves stream the same 3.2MB
// src tile together: the XCD L2 holds the live tile and each XCD reads X
// once (~102MB compulsory vs 147MB phase-mixed).
// mode 0: out = bf16(acc * norm^2) -> X2;  mode 1: out = bf16(acc * norm) -> Yb
__global__ __launch_bounds__(256) void k_gather(const unsigned short* __restrict__ Xin,
        const int* __restrict__ rowptr, const int4* __restrict__ tptr,
        const int* __restrict__ srclist,
        const float* __restrict__ norm, unsigned short* __restrict__ outp,
        int mode) {
    int wid = (blockIdx.x * 256 + threadIdx.x) >> 6;
    int lane = threadIdx.x & 63;
    int grp = lane >> 4;
    int c8 = (lane & 15) << 3;
    const unsigned short* xb = Xin + c8;

    int n0 = wid * 8 + grp;      // quad-0 node for this group
    int n1 = n0 + 4;             // quad-1 node
    bool val0 = (n0 < NN), val1 = (n1 < NN);

    int4 tp0 = val0 ? tptr[n0] : (int4){0, 0, 0, 0};
    int  e0  = val0 ? rowptr[n0 + 1] : 0;
    int4 tp1 = val1 ? tptr[n1] : (int4){0, 0, 0, 0};
    int  e1  = val1 ? rowptr[n1 + 1] : 0;

    int st0[5] = {tp0.x, tp0.y, tp0.z, tp0.w, e0};
    int st1[5] = {tp1.x, tp1.y, tp1.z, tp1.w, e1};

    f32x2 a0[4], a1[4];
    #pragma unroll
    for (int k = 0; k < 4; ++k) { a0[k] = (f32x2){0.f, 0.f}; a1[k] = (f32x2){0.f, 0.f}; }

    #pragma unroll
    for (int t = 0; t < 4; ++t) {
        // quad 0 segment for tile t
        int j = st0[t], je = st0[t + 1];
        for (; j + 3 < je; j += 4) {
            int s0 = srclist[j];
            int s1 = srclist[j + 1];
            int s2 = srclist[j + 2];
            int s3 = srclist[j + 3];
            uint4 r0 = *(const uint4*)(xb + s0);
            uint4 r1 = *(const uint4*)(xb + s1);
            uint4 r2 = *(const uint4*)(xb + s2);
            uint4 r3 = *(const uint4*)(xb + s3);
            accp(a0, r0); accp(a0, r1); accp(a0, r2); accp(a0, r3);
        }
        for (; j < je; ++j) {
            int s = srclist[j];
            uint4 v = *(const uint4*)(xb + s);
            accp(a0, v);
        }
        // quad 1 segment for tile t
        j = st1[t]; je = st1[t + 1];
        for (; j + 3 < je; j += 4) {
            int s0 = srclist[j];
            int s1 = srclist[j + 1];
            int s2 = srclist[j + 2];
            int s3 = srclist[j + 3];
            uint4 r0 = *(const uint4*)(xb + s0);
            uint4 r1 = *(const uint4*)(xb + s1);
            uint4 r2 = *(const uint4*)(xb + s2);
            uint4 r3 = *(const uint4*)(xb + s3);
            accp(a1, r0); accp(a1, r1); accp(a1, r2); accp(a1, r3);
        }
        for (; j < je; ++j) {
            int s = srclist[j];
            uint4 v = *(const uint4*)(xb + s);
            accp(a1, v);
        }
    }

    if (val0) {
        float nm = norm[n0];
        float sc = (mode == 0) ? nm * nm : nm;
        uint4 o;
        o.x = ((unsigned)f2bf(a0[0][1] * sc) << 16) | (unsigned)f2bf(a0[0][0] * sc);
        o.y = ((unsigned)f2bf(a0[1][1] * sc) << 16) | (unsigned)f2bf(a0[1][0] * sc);
        o.z = ((unsigned)f2bf(a0[2][1] * sc) << 16) | (unsigned)f2bf(a0[2][0] * sc);
        o.w = ((unsigned)f2bf(a0[3][1] * sc) << 16) | (unsigned)f2bf(a0[3][0] * sc);
        *(uint4*)(outp + n0 * DD + c8) = o;
    }
    if (val1) {
        float nm = norm[n1];
        float sc = (mode == 0) ? nm * nm : nm;
        uint4 o;
        o.x = ((unsigned)f2bf(a1[0][1] * sc) << 16) | (unsigned)f2bf(a1[0][0] * sc);
        o.y = ((unsigned)f2bf(a1[1][1] * sc) << 16) | (unsigned)f2bf(a1[1][0] * sc);
        o.z = ((unsigned)f2bf(a1[2][1] * sc) << 16) | (unsigned)f2bf(a1[2][0] * sc);
        o.w = ((unsigned)f2bf(a1[3][1] * sc) << 16) | (unsigned)f2bf(a1[3][0] * sc);
        *(uint4*)(outp + n1 * DD + c8) = o;
    }
}

// MFMA GEMM: out[n,o] = Yb[n,:] @ W[o,:] + b[o].  Yb bf16 (norm applied).
__global__ __launch_bounds__(256) void k_gemm2(const unsigned short* __restrict__ Yb,
        const void* __restrict__ Wp, const void* __restrict__ bp,
        void* __restrict__ outp, const int* __restrict__ flags) {
    __shared__ unsigned short Wl[DD * 136];
    int tid = threadIdx.x;
    int wf32 = flags[2], of32 = flags[1];

    for (int i = tid; i < 8192; i += 256) {
        int r = i >> 6, cc = i & 63;
        unsigned pk;
        if (wf32) {
            float2 w = ((const float2*)Wp)[i];
            pk = ((unsigned)f2bf(w.y) << 16) | (unsigned)f2bf(w.x);
        } else {
            pk = ((const unsigned*)Wp)[i];
        }
        *(unsigned*)&Wl[r * 136 + cc * 2] = pk;
    }
    __syncthreads();

    int wave = tid >> 6, lane = tid & 63;
    int nb = blockIdx.x * 64 + wave * 16;
    int m = lane & 15, quad = lane >> 4;
    int arow = nb + m; if (arow >= NN) arow = NN - 1;
    const unsigned short* arp = Yb + arow * DD + quad * 8;

    ffrag acc[8];
    #pragma unroll
    for (int t = 0; t < 8; ++t) acc[t] = (ffrag){0.f, 0.f, 0.f, 0.f};

    #pragma unroll
    for (int c = 0; c < 4; ++c) {
        bfrag af = *(const bfrag*)(arp + c * 32);
        #pragma unroll
        for (int t = 0; t < 8; ++t) {
            bfrag bf = *(const bfrag*)&Wl[(t * 16 + m) * 136 + c * 32 + quad * 8];
            acc[t] = __builtin_amdgcn_mfma_f32_16x16x32_bf16(af, bf, acc[t], 0, 0, 0);
        }
    }

    #pragma unroll
    for (int t = 0; t < 8; ++t) {
        int o = t * 16 + m;
        float bias = wf32 ? ((const float*)bp)[o] : bf2f(((const unsigned short*)bp)[o]);
        #pragma unroll
        for (int r = 0; r < 4; ++r) {
            int n = nb + quad * 4 + r;
            if (n < NN) {
                float v = acc[t][r] + bias;
                if (of32) ((float*)outp)[n * DD + o] = v;
                else      ((unsigned short*)outp)[n * DD + o] = f2bf(v);
            }
        }
    }
}

extern "C" void kernel_launch(void* const* d_in, const int* in_sizes, int n_in,
                              void* d_out, int out_size, void* d_ws, size_t ws_size,
                              hipStream_t stream) {
    const void* feat = d_in[0];
    const void* src  = d_in[1];
    const void* dst  = d_in[2];
    const void* W    = d_in[3];
    const void* b    = d_in[4];

    // ws (bytes): flags@0 | rowptr@64 | norm@200128 | cnt@400128 | loff@600832 |
    //   binsum@801536 | binoff@802560 | tptr@803584 (800KB) | srclist@1603584 |
    //   X1@8003584 | X2@20803840. staged aliases X2's first 6.4MB (dead before
    //   gather-0 writes X2). end ~33.6MB
    char* wsb = (char*)d_ws;
    int*   flags   = (int*)wsb;
    int*   rowptr  = (int*)(wsb + 64);
    float* norm    = (float*)(wsb + 200128);
    int*   cnt     = (int*)(wsb + 400128);
    int*   loff    = (int*)(wsb + 600832);
    int*   binsum  = (int*)(wsb + 801536);
    int*   binoff  = (int*)(wsb + 802560);
    int4*  tptr    = (int4*)(wsb + 803584);
    int*   srclist = (int*)(wsb + 1603584);
    unsigned short* X1 = (unsigned short*)(wsb + 8003584);   // hop-1 input, then Yb
    unsigned short* X2 = (unsigned short*)(wsb + 20803840);
    unsigned* staged   = (unsigned*)(wsb + 20803840);

    k_detect<<<1, 256, 0, stream>>>((const int*)src, (const int*)dst,
                                    (const unsigned short*)feat,
                                    (const unsigned short*)W, flags);
    k_count<<<NCH, 256, 0, stream>>>(dst, cnt, flags);
    k_scan2<<<NB, 256, 0, stream>>>(cnt, loff, binsum);
    k_scanbin<<<1, 256, 0, stream>>>(binsum, binoff, rowptr);
    k_stage<<<NCH, 256, 0, stream>>>(src, dst, binoff, loff, staged, flags);
    k_fill<<<NB, 512, 0, stream>>>(staged, binoff, rowptr, tptr, norm, srclist);
    k_prescale<<<(NN * DD / 4 + 255) / 256, 256, 0, stream>>>(feat, norm, X1, flags);
    k_gather<<<GBLK, 256, 0, stream>>>(X1, rowptr, tptr, srclist, norm, X2, 0);
    k_gather<<<GBLK, 256, 0, stream>>>(X2, rowptr, tptr, srclist, norm, X1, 1);
    k_gemm2<<<(NN + 63) / 64, 256, 0, stream>>>(X1, W, b, d_out, flags);
}